// Round 2
// baseline (1181.670 us; speedup 1.0000x reference)
//
#include <hip/hip_runtime.h>
#include <hip/hip_bf16.h>
#include <math.h>

// ---------------- graph structure ----------------

__global__ void count_indeg(const int* __restrict__ dst, int e, int* __restrict__ indeg) {
    int i = blockIdx.x * blockDim.x + threadIdx.x;
    if (i < e) atomicAdd(&indeg[dst[i]], 1);
}

__global__ void compute_dinv(const int* __restrict__ indeg, float* __restrict__ dinv, int n) {
    int i = blockIdx.x * blockDim.x + threadIdx.x;
    if (i < n) {
        float deg = (float)(indeg[i] + 1);   // + self loop, always >= 1
        dinv[i] = 1.0f / sqrtf(deg);
    }
}

// disjoint ranges via one global counter; order across nodes irrelevant
__global__ void make_ranges(const int* __restrict__ indeg, int* __restrict__ start,
                            int* __restrict__ cursor, int* __restrict__ counter, int n) {
    int i = blockIdx.x * blockDim.x + threadIdx.x;
    if (i < n) {
        int s = atomicAdd(counter, indeg[i]);
        start[i] = s;
        cursor[i] = s;
    }
}

__global__ void fill_csr(const int* __restrict__ src, const int* __restrict__ dst, int e,
                         int* __restrict__ cursor, int* __restrict__ ssrc) {
    int i = blockIdx.x * blockDim.x + threadIdx.x;
    if (i < e) {
        int p = atomicAdd(&cursor[dst[i]], 1);
        if (p >= 0 && p < e) ssrc[p] = src[i];
    }
}

// ---------------- weight fake-quant (symmetric 4-bit) ----------------

__global__ void quant_w(const float* __restrict__ w, const float* __restrict__ a,
                        float* __restrict__ wq, int n) {
    int i = blockIdx.x * blockDim.x + threadIdx.x;
    if (i < n) {
        float s = a[0];
        float v = w[i] / s;
        v = fminf(fmaxf(v, -8.0f), 7.0f);
        wq[i] = rintf(v) * s;   // round-half-even, matches jnp.round
    }
}

// ---------------- naive GEMM: C[M,N] = A[M,K] @ B[K,N] + bias[N] ----------------
// One thread per output element. Coalesced over j; B (<=64KB) is L2-resident.

__global__ void gemm_bias_naive(const float* __restrict__ A, const float* __restrict__ B,
                                const float* __restrict__ bias, float* __restrict__ C,
                                int M, int N, int K) {
    int idx = blockIdx.x * blockDim.x + threadIdx.x;
    if (idx >= M * N) return;
    int m = idx / N;
    int j = idx - m * N;
    const float* a = A + (size_t)m * K;
    float acc = 0.0f;
    for (int k = 0; k < K; ++k) acc = fmaf(a[k], B[(size_t)k * N + j], acc);
    C[idx] = acc + bias[j];
}

// ---------------- GCN aggregation (gather, defensive) ----------------

__global__ void aggregate(const float* __restrict__ h, const float* __restrict__ dinv,
                          const int* __restrict__ start, const int* __restrict__ indeg,
                          const int* __restrict__ ssrc, float* __restrict__ out,
                          int n, int C, int E) {
    int node = blockIdx.x;
    if (node >= n) return;
    int c = threadIdx.x;
    bool act = c < C;
    float di = dinv[node];
    float acc = act ? h[(size_t)node * C + c] * di * di : 0.0f;   // self loop
    int s0 = start[node];
    int len = indeg[node];
    if (s0 < 0) s0 = 0;
    if (len < 0) len = 0;
    if (s0 + len > E) len = (E - s0 > 0) ? (E - s0) : 0;
    for (int j = 0; j < len; ++j) {
        int s = ssrc[s0 + j];
        if (s < 0 || s >= n) continue;    // defensive: poison -> skip, not OOB
        if (act) acc += h[(size_t)s * C + c] * (dinv[s] * di);
    }
    if (act) out[(size_t)node * C + c] = acc;
}

// ---------------- BatchNorm ----------------

__global__ void bn_stats(const float* __restrict__ x, int n,
                         float* __restrict__ sums, float* __restrict__ sumsq) {
    int c = threadIdx.x;   // 128
    float s = 0.f, s2 = 0.f;
    for (int r = blockIdx.x; r < n; r += gridDim.x) {
        float v = x[(size_t)r * 128 + c];
        s += v; s2 += v * v;
    }
    atomicAdd(&sums[c], s);
    atomicAdd(&sumsq[c], s2);
}

__global__ void bn_finalize(const float* __restrict__ sums, const float* __restrict__ sumsq,
                            const float* __restrict__ g, const float* __restrict__ b,
                            int n, float* __restrict__ A, float* __restrict__ Bout) {
    int c = threadIdx.x;   // 128
    float m = sums[c] / (float)n;
    float v = sumsq[c] / (float)n - m * m;
    float a = g[c] * (1.0f / sqrtf(v + 1e-5f));
    A[c] = a;
    Bout[c] = b[c] - m * a;
}

// BN affine + ReLU + unsigned 4-bit fake-quant (per-node scale gs[row])
__global__ void bn_apply_quant(const float* __restrict__ x, const float* __restrict__ A,
                               const float* __restrict__ Bp, const float* __restrict__ gs,
                               float* __restrict__ out, int n) {
    int idx = blockIdx.x * blockDim.x + threadIdx.x;
    if (idx >= n * 128) return;
    int c = idx & 127;
    int r = idx >> 7;
    float v = A[c] * x[idx] + Bp[c];
    v = fmaxf(v, 0.0f);
    float s = gs[r];
    float q = fminf(fmaxf(v / s, 0.0f), 15.0f);
    out[idx] = rintf(q) * s;
}

// ---------------- log_softmax (one wave per row, in-place safe) ----------------

__global__ void log_softmax_rows(const float* __restrict__ z, float* __restrict__ out,
                                 int n, int C) {
    int rowsPerBlock = blockDim.x / 64;
    int row = blockIdx.x * rowsPerBlock + (threadIdx.x / 64);
    int lane = threadIdx.x & 63;
    if (row >= n) return;
    float v = (lane < C) ? z[(size_t)row * C + lane] : -INFINITY;
    float m = v;
#pragma unroll
    for (int o = 32; o; o >>= 1) m = fmaxf(m, __shfl_xor(m, o));
    float e = (lane < C) ? expf(v - m) : 0.0f;
    float s = e;
#pragma unroll
    for (int o = 32; o; o >>= 1) s += __shfl_xor(s, o);
    if (lane < C) out[(size_t)row * C + lane] = v - m - logf(s);
}

// ---------------- launch ----------------

extern "C" void kernel_launch(void* const* d_in, const int* in_sizes, int n_in,
                              void* d_out, int out_size, void* d_ws, size_t ws_size,
                              hipStream_t stream) {
    float*       xbuf = (float*)d_in[0];          // reused as scratch after layer-1 GEMM
    const int*   ei   = (const int*)d_in[1];
    const float* W1   = (const float*)d_in[2];
    const float* b1   = (const float*)d_in[3];
    const float* a1   = (const float*)d_in[4];
    const float* W2   = (const float*)d_in[5];
    const float* b2   = (const float*)d_in[6];
    const float* a2   = (const float*)d_in[7];
    const float* g2   = (const float*)d_in[8];
    const float* W3   = (const float*)d_in[9];
    const float* b3   = (const float*)d_in[10];
    const float* a3   = (const float*)d_in[11];
    const float* g3   = (const float*)d_in[12];
    const float* bn1g = (const float*)d_in[13];
    const float* bn1b = (const float*)d_in[14];
    const float* bn2g = (const float*)d_in[15];
    const float* bn2b = (const float*)d_in[16];

    const int n = in_sizes[0] / 128;      // 50000
    const int E = in_sizes[1] / 2;        // 800000
    const int C = in_sizes[9] / 128;      // 40
    const int* src = ei;
    const int* dst = ei + E;

    // ---- workspace layout (~30 MB) ----
    char* wsp = (char*)d_ws;
    size_t off = 0;
    auto take = [&](size_t bytes) -> void* {
        void* p = wsp + off;
        off += (bytes + 255) & ~(size_t)255;
        return p;
    };
    int*   indeg   = (int*)take((size_t)n * 4);
    int*   startA  = (int*)take((size_t)n * 4);
    int*   cursor  = (int*)take((size_t)n * 4);
    float* dinv    = (float*)take((size_t)n * 4);
    int*   counter = (int*)take(4);
    int*   ssrc    = (int*)take((size_t)E * 4);
    float* w1q     = (float*)take(128 * 128 * 4);
    float* w2q     = (float*)take(128 * 128 * 4);
    float* w3q     = (float*)take((size_t)128 * C * 4);
    float* stats   = (float*)take(512 * 4);
    float* hbuf    = (float*)take((size_t)n * 128 * 4);

    float* sums  = stats;
    float* sumsq = stats + 128;
    float* bnA   = stats + 256;
    float* bnB   = stats + 384;
    float* outF  = (float*)d_out;

    // ---- graph structure (rebuilt every call; ws is poisoned) ----
    hipMemsetAsync(indeg, 0, (size_t)n * 4, stream);
    hipMemsetAsync(counter, 0, 4, stream);
    count_indeg<<<(E + 255) / 256, 256, 0, stream>>>(dst, E, indeg);
    compute_dinv<<<(n + 255) / 256, 256, 0, stream>>>(indeg, dinv, n);
    make_ranges<<<(n + 255) / 256, 256, 0, stream>>>(indeg, startA, cursor, counter, n);
    fill_csr<<<(E + 255) / 256, 256, 0, stream>>>(src, dst, E, cursor, ssrc);

    // ---- weight fake-quant ----
    quant_w<<<(128 * 128 + 255) / 256, 256, 0, stream>>>(W1, a1, w1q, 128 * 128);
    quant_w<<<(128 * 128 + 255) / 256, 256, 0, stream>>>(W2, a2, w2q, 128 * 128);
    quant_w<<<(128 * C + 255) / 256, 256, 0, stream>>>(W3, a3, w3q, 128 * C);

    const int nElem128 = n * 128;
    const int gElem128 = (nElem128 + 255) / 256;

    // ---- layer 1 ----
    gemm_bias_naive<<<gElem128, 256, 0, stream>>>(xbuf, w1q, b1, hbuf, n, 128, 128);
    aggregate<<<n, 128, 0, stream>>>(hbuf, dinv, startA, indeg, ssrc, xbuf, n, 128, E);
    hipMemsetAsync(stats, 0, 256 * 4, stream);
    bn_stats<<<512, 128, 0, stream>>>(xbuf, n, sums, sumsq);
    bn_finalize<<<1, 128, 0, stream>>>(sums, sumsq, bn1g, bn1b, n, bnA, bnB);
    bn_apply_quant<<<gElem128, 256, 0, stream>>>(xbuf, bnA, bnB, g2, hbuf, n);

    // ---- layer 2 ----
    gemm_bias_naive<<<gElem128, 256, 0, stream>>>(hbuf, w2q, b2, xbuf, n, 128, 128);
    aggregate<<<n, 128, 0, stream>>>(xbuf, dinv, startA, indeg, ssrc, hbuf, n, 128, E);
    hipMemsetAsync(stats, 0, 256 * 4, stream);
    bn_stats<<<512, 128, 0, stream>>>(hbuf, n, sums, sumsq);
    bn_finalize<<<1, 128, 0, stream>>>(sums, sumsq, bn2g, bn2b, n, bnA, bnB);
    bn_apply_quant<<<gElem128, 256, 0, stream>>>(hbuf, bnA, bnB, g3, xbuf, n);

    // ---- layer 3 ----
    const int nElemC = n * C;
    gemm_bias_naive<<<(nElemC + 255) / 256, 256, 0, stream>>>(xbuf, w3q, b3, hbuf, n, C, 128);
    aggregate<<<n, 64, 0, stream>>>(hbuf, dinv, startA, indeg, ssrc, outF, n, C, E);
    log_softmax_rows<<<(n + 3) / 4, 256, 0, stream>>>(outF, outF, n, C);
}

// Round 3
// 658.074 us; speedup vs baseline: 1.7956x; 1.7956x over previous
//
#include <hip/hip_runtime.h>
#include <hip/hip_bf16.h>
#include <math.h>

// ---------------- graph structure ----------------

__global__ void count_indeg(const int* __restrict__ dst, int e, int* __restrict__ indeg) {
    int i = blockIdx.x * blockDim.x + threadIdx.x;
    if (i < e) atomicAdd(&indeg[dst[i]], 1);
}

__global__ void compute_dinv(const int* __restrict__ indeg, float* __restrict__ dinv, int n) {
    int i = blockIdx.x * blockDim.x + threadIdx.x;
    if (i < n) {
        float deg = (float)(indeg[i] + 1);   // + self loop, always >= 1
        dinv[i] = 1.0f / sqrtf(deg);
    }
}

// disjoint ranges via one global counter; order across nodes irrelevant
__global__ void make_ranges(const int* __restrict__ indeg, int* __restrict__ start,
                            int* __restrict__ cursor, int* __restrict__ counter, int n) {
    int i = blockIdx.x * blockDim.x + threadIdx.x;
    if (i < n) {
        int s = atomicAdd(counter, indeg[i]);
        start[i] = s;
        cursor[i] = s;
    }
}

__global__ void fill_csr(const int* __restrict__ src, const int* __restrict__ dst, int e,
                         int* __restrict__ cursor, int* __restrict__ ssrc) {
    int i = blockIdx.x * blockDim.x + threadIdx.x;
    if (i < e) {
        int p = atomicAdd(&cursor[dst[i]], 1);
        if (p >= 0 && p < e) ssrc[p] = src[i];
    }
}

// ---------------- weight fake-quant (symmetric 4-bit) ----------------

__global__ void quant_w(const float* __restrict__ w, const float* __restrict__ a,
                        float* __restrict__ wq, int n) {
    int i = blockIdx.x * blockDim.x + threadIdx.x;
    if (i < n) {
        float s = a[0];
        float v = w[i] / s;
        v = fminf(fmaxf(v, -8.0f), 7.0f);
        wq[i] = rintf(v) * s;   // round-half-even, matches jnp.round
    }
}

// ---------------- tiled GEMM: C[M,N] = A[M,K] @ B[K,N] + bias[N] ----------------
// 128x64 tile, 256 threads, 8x4 microtile, K chunked by 16. float4 LDS traffic.

#define TM 128
#define TN 64
#define TK 16

__global__ __launch_bounds__(256) void gemm_bias_tiled(
        const float* __restrict__ A, const float* __restrict__ B,
        const float* __restrict__ bias, float* __restrict__ C,
        int M, int N, int K) {
    __shared__ float sA[TK][TM + 4];
    __shared__ float sB[TK][TN + 4];
    int tid = threadIdx.x;
    int rowBase = blockIdx.x * TM;
    int colBase = blockIdx.y * TN;
    int tx = tid & 15;       // -> 4 cols at tx*4
    int ty = tid >> 4;       // -> 8 rows at ty*8
    float acc[8][4] = {};

    // A staging: 128 rows x 16 k per chunk; thread -> row tid/2, k (tid&1)*8 (two float4)
    int aRow = tid >> 1;
    int aK   = (tid & 1) * 8;
    // B staging: 16 k x 64 cols; thread -> k tid/16, col (tid&15)*4 (one float4)
    int bK   = tid >> 4;
    int bCol = (tid & 15) * 4;

    for (int k0 = 0; k0 < K; k0 += TK) {
        int gRow = rowBase + aRow;
        if (gRow >= M) gRow = M - 1;            // clamp; discarded at store
        const float* ap = A + (size_t)gRow * K + k0 + aK;
        float4 a0 = *(const float4*)ap;
        float4 a1 = *(const float4*)(ap + 4);
        sA[aK + 0][aRow] = a0.x;
        sA[aK + 1][aRow] = a0.y;
        sA[aK + 2][aRow] = a0.z;
        sA[aK + 3][aRow] = a0.w;
        sA[aK + 4][aRow] = a1.x;
        sA[aK + 5][aRow] = a1.y;
        sA[aK + 6][aRow] = a1.z;
        sA[aK + 7][aRow] = a1.w;

        int col = colBase + bCol;
        const float* bp = B + (size_t)(k0 + bK) * N + col;
        if (col + 3 < N) {
            *(float4*)&sB[bK][bCol] = *(const float4*)bp;
        } else {
#pragma unroll
            for (int j = 0; j < 4; ++j)
                sB[bK][bCol + j] = (col + j < N) ? bp[j] : 0.0f;
        }
        __syncthreads();

#pragma unroll
        for (int kk = 0; kk < TK; ++kk) {
            float4 av0 = *(const float4*)&sA[kk][ty * 8];
            float4 av1 = *(const float4*)&sA[kk][ty * 8 + 4];
            float4 bv  = *(const float4*)&sB[kk][tx * 4];
            float a[8] = {av0.x, av0.y, av0.z, av0.w, av1.x, av1.y, av1.z, av1.w};
            float b[4] = {bv.x, bv.y, bv.z, bv.w};
#pragma unroll
            for (int i = 0; i < 8; ++i)
#pragma unroll
                for (int j = 0; j < 4; ++j)
                    acc[i][j] = fmaf(a[i], b[j], acc[i][j]);
        }
        __syncthreads();
    }

    int colOut = colBase + tx * 4;
    float bb[4];
#pragma unroll
    for (int j = 0; j < 4; ++j) bb[j] = (colOut + j < N) ? bias[colOut + j] : 0.0f;
#pragma unroll
    for (int i = 0; i < 8; ++i) {
        int row = rowBase + ty * 8 + i;
        if (row >= M) continue;
        if (colOut + 3 < N) {
            float4 v = {acc[i][0] + bb[0], acc[i][1] + bb[1],
                        acc[i][2] + bb[2], acc[i][3] + bb[3]};
            *(float4*)&C[(size_t)row * N + colOut] = v;
        } else {
#pragma unroll
            for (int j = 0; j < 4; ++j)
                if (colOut + j < N) C[(size_t)row * N + colOut + j] = acc[i][j] + bb[j];
        }
    }
}

// ---------------- GCN aggregation (gather, defensive) ----------------

__global__ void aggregate(const float* __restrict__ h, const float* __restrict__ dinv,
                          const int* __restrict__ start, const int* __restrict__ indeg,
                          const int* __restrict__ ssrc, float* __restrict__ out,
                          int n, int C, int E) {
    int node = blockIdx.x;
    if (node >= n) return;
    int c = threadIdx.x;
    bool act = c < C;
    float di = dinv[node];
    float acc = act ? h[(size_t)node * C + c] * di * di : 0.0f;   // self loop
    int s0 = start[node];
    int len = indeg[node];
    if (s0 < 0) s0 = 0;
    if (len < 0) len = 0;
    if (s0 + len > E) len = (E - s0 > 0) ? (E - s0) : 0;
    for (int j = 0; j < len; ++j) {
        int s = ssrc[s0 + j];
        if (s < 0 || s >= n) continue;    // defensive: poison -> skip, not OOB
        if (act) acc += h[(size_t)s * C + c] * (dinv[s] * di);
    }
    if (act) out[(size_t)node * C + c] = acc;
}

// ---------------- BatchNorm ----------------

__global__ void bn_stats(const float* __restrict__ x, int n,
                         float* __restrict__ sums, float* __restrict__ sumsq) {
    int c = threadIdx.x;   // 128
    float s = 0.f, s2 = 0.f;
    for (int r = blockIdx.x; r < n; r += gridDim.x) {
        float v = x[(size_t)r * 128 + c];
        s += v; s2 += v * v;
    }
    atomicAdd(&sums[c], s);
    atomicAdd(&sumsq[c], s2);
}

__global__ void bn_finalize(const float* __restrict__ sums, const float* __restrict__ sumsq,
                            const float* __restrict__ g, const float* __restrict__ b,
                            int n, float* __restrict__ A, float* __restrict__ Bout) {
    int c = threadIdx.x;   // 128
    float m = sums[c] / (float)n;
    float v = sumsq[c] / (float)n - m * m;
    float a = g[c] * (1.0f / sqrtf(v + 1e-5f));
    A[c] = a;
    Bout[c] = b[c] - m * a;
}

// BN affine + ReLU + unsigned 4-bit fake-quant (per-node scale gs[row])
__global__ void bn_apply_quant(const float* __restrict__ x, const float* __restrict__ A,
                               const float* __restrict__ Bp, const float* __restrict__ gs,
                               float* __restrict__ out, int n) {
    int idx = blockIdx.x * blockDim.x + threadIdx.x;
    if (idx >= n * 128) return;
    int c = idx & 127;
    int r = idx >> 7;
    float v = A[c] * x[idx] + Bp[c];
    v = fmaxf(v, 0.0f);
    float s = gs[r];
    float q = fminf(fmaxf(v / s, 0.0f), 15.0f);
    out[idx] = rintf(q) * s;
}

// ---------------- log_softmax (one wave per row, in-place safe) ----------------

__global__ void log_softmax_rows(const float* __restrict__ z, float* __restrict__ out,
                                 int n, int C) {
    int rowsPerBlock = blockDim.x / 64;
    int row = blockIdx.x * rowsPerBlock + (threadIdx.x / 64);
    int lane = threadIdx.x & 63;
    if (row >= n) return;
    float v = (lane < C) ? z[(size_t)row * C + lane] : -INFINITY;
    float m = v;
#pragma unroll
    for (int o = 32; o; o >>= 1) m = fmaxf(m, __shfl_xor(m, o));
    float e = (lane < C) ? expf(v - m) : 0.0f;
    float s = e;
#pragma unroll
    for (int o = 32; o; o >>= 1) s += __shfl_xor(s, o);
    if (lane < C) out[(size_t)row * C + lane] = v - m - logf(s);
}

// ---------------- launch ----------------

extern "C" void kernel_launch(void* const* d_in, const int* in_sizes, int n_in,
                              void* d_out, int out_size, void* d_ws, size_t ws_size,
                              hipStream_t stream) {
    float*       xbuf = (float*)d_in[0];          // reused as scratch after layer-1 GEMM
    const int*   ei   = (const int*)d_in[1];
    const float* W1   = (const float*)d_in[2];
    const float* b1   = (const float*)d_in[3];
    const float* a1   = (const float*)d_in[4];
    const float* W2   = (const float*)d_in[5];
    const float* b2   = (const float*)d_in[6];
    const float* a2   = (const float*)d_in[7];
    const float* g2   = (const float*)d_in[8];
    const float* W3   = (const float*)d_in[9];
    const float* b3   = (const float*)d_in[10];
    const float* a3   = (const float*)d_in[11];
    const float* g3   = (const float*)d_in[12];
    const float* bn1g = (const float*)d_in[13];
    const float* bn1b = (const float*)d_in[14];
    const float* bn2g = (const float*)d_in[15];
    const float* bn2b = (const float*)d_in[16];

    const int n = in_sizes[0] / 128;      // 50000
    const int E = in_sizes[1] / 2;        // 800000
    const int C = in_sizes[9] / 128;      // 40
    const int* src = ei;
    const int* dst = ei + E;

    // ---- workspace layout (~30 MB) ----
    char* wsp = (char*)d_ws;
    size_t off = 0;
    auto take = [&](size_t bytes) -> void* {
        void* p = wsp + off;
        off += (bytes + 255) & ~(size_t)255;
        return p;
    };
    int*   indeg   = (int*)take((size_t)n * 4);
    int*   startA  = (int*)take((size_t)n * 4);
    int*   cursor  = (int*)take((size_t)n * 4);
    float* dinv    = (float*)take((size_t)n * 4);
    int*   counter = (int*)take(4);
    int*   ssrc    = (int*)take((size_t)E * 4);
    float* w1q     = (float*)take(128 * 128 * 4);
    float* w2q     = (float*)take(128 * 128 * 4);
    float* w3q     = (float*)take((size_t)128 * C * 4);
    float* stats   = (float*)take(512 * 4);
    float* hbuf    = (float*)take((size_t)n * 128 * 4);

    float* sums  = stats;
    float* sumsq = stats + 128;
    float* bnA   = stats + 256;
    float* bnB   = stats + 384;
    float* outF  = (float*)d_out;

    // ---- graph structure (rebuilt every call; ws is poisoned) ----
    hipMemsetAsync(indeg, 0, (size_t)n * 4, stream);
    hipMemsetAsync(counter, 0, 4, stream);
    count_indeg<<<(E + 255) / 256, 256, 0, stream>>>(dst, E, indeg);
    compute_dinv<<<(n + 255) / 256, 256, 0, stream>>>(indeg, dinv, n);
    make_ranges<<<(n + 255) / 256, 256, 0, stream>>>(indeg, startA, cursor, counter, n);
    fill_csr<<<(E + 255) / 256, 256, 0, stream>>>(src, dst, E, cursor, ssrc);

    // ---- weight fake-quant ----
    quant_w<<<(128 * 128 + 255) / 256, 256, 0, stream>>>(W1, a1, w1q, 128 * 128);
    quant_w<<<(128 * 128 + 255) / 256, 256, 0, stream>>>(W2, a2, w2q, 128 * 128);
    quant_w<<<(128 * C + 255) / 256, 256, 0, stream>>>(W3, a3, w3q, 128 * C);

    const int nElem128 = n * 128;
    const int gElem128 = (nElem128 + 255) / 256;
    dim3 grid128((n + TM - 1) / TM, (128 + TN - 1) / TN);
    dim3 gridC((n + TM - 1) / TM, (C + TN - 1) / TN);

    // ---- layer 1 ----
    gemm_bias_tiled<<<grid128, 256, 0, stream>>>(xbuf, w1q, b1, hbuf, n, 128, 128);
    aggregate<<<n, 128, 0, stream>>>(hbuf, dinv, startA, indeg, ssrc, xbuf, n, 128, E);
    hipMemsetAsync(stats, 0, 256 * 4, stream);
    bn_stats<<<512, 128, 0, stream>>>(xbuf, n, sums, sumsq);
    bn_finalize<<<1, 128, 0, stream>>>(sums, sumsq, bn1g, bn1b, n, bnA, bnB);
    bn_apply_quant<<<gElem128, 256, 0, stream>>>(xbuf, bnA, bnB, g2, hbuf, n);

    // ---- layer 2 ----
    gemm_bias_tiled<<<grid128, 256, 0, stream>>>(hbuf, w2q, b2, xbuf, n, 128, 128);
    aggregate<<<n, 128, 0, stream>>>(xbuf, dinv, startA, indeg, ssrc, hbuf, n, 128, E);
    hipMemsetAsync(stats, 0, 256 * 4, stream);
    bn_stats<<<512, 128, 0, stream>>>(hbuf, n, sums, sumsq);
    bn_finalize<<<1, 128, 0, stream>>>(sums, sumsq, bn2g, bn2b, n, bnA, bnB);
    bn_apply_quant<<<gElem128, 256, 0, stream>>>(hbuf, bnA, bnB, g3, xbuf, n);

    // ---- layer 3 ----
    gemm_bias_tiled<<<gridC, 256, 0, stream>>>(xbuf, w3q, b3, hbuf, n, C, 128);
    aggregate<<<n, 64, 0, stream>>>(hbuf, dinv, startA, indeg, ssrc, outF, n, C, E);
    log_softmax_rows<<<(n + 3) / 4, 256, 0, stream>>>(outF, outF, n, C);
}

// Round 4
// 624.443 us; speedup vs baseline: 1.8924x; 1.0539x over previous
//
#include <hip/hip_runtime.h>
#include <hip/hip_bf16.h>
#include <math.h>

// ---------------- graph structure ----------------

__global__ void count_indeg(const int* __restrict__ dst, int e, int* __restrict__ indeg) {
    int i = blockIdx.x * blockDim.x + threadIdx.x;
    if (i < e) atomicAdd(&indeg[dst[i]], 1);
}

__global__ void compute_dinv(const int* __restrict__ indeg, float* __restrict__ dinv, int n) {
    int i = blockIdx.x * blockDim.x + threadIdx.x;
    if (i < n) {
        float deg = (float)(indeg[i] + 1);   // + self loop, always >= 1
        dinv[i] = 1.0f / sqrtf(deg);
    }
}

// disjoint ranges via one global counter; order across nodes irrelevant
__global__ void make_ranges(const int* __restrict__ indeg, int* __restrict__ start,
                            int* __restrict__ cursor, int* __restrict__ counter, int n) {
    int i = blockIdx.x * blockDim.x + threadIdx.x;
    if (i < n) {
        int s = atomicAdd(counter, indeg[i]);
        start[i] = s;
        cursor[i] = s;
    }
}

__global__ void fill_csr(const int* __restrict__ src, const int* __restrict__ dst, int e,
                         int* __restrict__ cursor, int* __restrict__ ssrc) {
    int i = blockIdx.x * blockDim.x + threadIdx.x;
    if (i < e) {
        int p = atomicAdd(&cursor[dst[i]], 1);
        if (p >= 0 && p < e) ssrc[p] = src[i];
    }
}

// ---------------- weight fake-quant (symmetric 4-bit) ----------------

__global__ void quant_w(const float* __restrict__ w, const float* __restrict__ a,
                        float* __restrict__ wq, int n) {
    int i = blockIdx.x * blockDim.x + threadIdx.x;
    if (i < n) {
        float s = a[0];
        float v = w[i] / s;
        v = fminf(fmaxf(v, -8.0f), 7.0f);
        wq[i] = rintf(v) * s;   // round-half-even, matches jnp.round
    }
}

// ---------------- tiled GEMM: C[M,N] = A[M,K] @ B[K,N] + bias[N] ----------------

#define TM 128
#define TN 64
#define TK 16

__global__ __launch_bounds__(256) void gemm_bias_tiled(
        const float* __restrict__ A, const float* __restrict__ B,
        const float* __restrict__ bias, float* __restrict__ C,
        int M, int N, int K) {
    __shared__ float sA[TK][TM + 4];
    __shared__ float sB[TK][TN + 4];
    int tid = threadIdx.x;
    int rowBase = blockIdx.x * TM;
    int colBase = blockIdx.y * TN;
    int tx = tid & 15;       // -> 4 cols at tx*4
    int ty = tid >> 4;       // -> 8 rows at ty*8
    float acc[8][4] = {};

    int aRow = tid >> 1;
    int aK   = (tid & 1) * 8;
    int bK   = tid >> 4;
    int bCol = (tid & 15) * 4;

    for (int k0 = 0; k0 < K; k0 += TK) {
        int gRow = rowBase + aRow;
        if (gRow >= M) gRow = M - 1;            // clamp; discarded at store
        const float* ap = A + (size_t)gRow * K + k0 + aK;
        float4 a0 = *(const float4*)ap;
        float4 a1 = *(const float4*)(ap + 4);
        sA[aK + 0][aRow] = a0.x;
        sA[aK + 1][aRow] = a0.y;
        sA[aK + 2][aRow] = a0.z;
        sA[aK + 3][aRow] = a0.w;
        sA[aK + 4][aRow] = a1.x;
        sA[aK + 5][aRow] = a1.y;
        sA[aK + 6][aRow] = a1.z;
        sA[aK + 7][aRow] = a1.w;

        int col = colBase + bCol;
        const float* bp = B + (size_t)(k0 + bK) * N + col;
        if (col + 3 < N) {
            *(float4*)&sB[bK][bCol] = *(const float4*)bp;
        } else {
#pragma unroll
            for (int j = 0; j < 4; ++j)
                sB[bK][bCol + j] = (col + j < N) ? bp[j] : 0.0f;
        }
        __syncthreads();

#pragma unroll
        for (int kk = 0; kk < TK; ++kk) {
            float4 av0 = *(const float4*)&sA[kk][ty * 8];
            float4 av1 = *(const float4*)&sA[kk][ty * 8 + 4];
            float4 bv  = *(const float4*)&sB[kk][tx * 4];
            float a[8] = {av0.x, av0.y, av0.z, av0.w, av1.x, av1.y, av1.z, av1.w};
            float b[4] = {bv.x, bv.y, bv.z, bv.w};
#pragma unroll
            for (int i = 0; i < 8; ++i)
#pragma unroll
                for (int j = 0; j < 4; ++j)
                    acc[i][j] = fmaf(a[i], b[j], acc[i][j]);
        }
        __syncthreads();
    }

    int colOut = colBase + tx * 4;
    float bb[4];
#pragma unroll
    for (int j = 0; j < 4; ++j) bb[j] = (colOut + j < N) ? bias[colOut + j] : 0.0f;
#pragma unroll
    for (int i = 0; i < 8; ++i) {
        int row = rowBase + ty * 8 + i;
        if (row >= M) continue;
        if (colOut + 3 < N) {
            float4 v = {acc[i][0] + bb[0], acc[i][1] + bb[1],
                        acc[i][2] + bb[2], acc[i][3] + bb[3]};
            *(float4*)&C[(size_t)row * N + colOut] = v;
        } else {
#pragma unroll
            for (int j = 0; j < 4; ++j)
                if (colOut + j < N) C[(size_t)row * N + colOut + j] = acc[i][j] + bb[j];
        }
    }
}

// ---------------- GCN aggregation: edge-parallel within node ----------------
// 128 channels: 256 threads = 8 edge-slots x 32 lanes x float4 (one 512B row per slot).

__global__ __launch_bounds__(256) void aggregate128_par(
        const float* __restrict__ h, const float* __restrict__ dinv,
        const int* __restrict__ start, const int* __restrict__ indeg,
        const int* __restrict__ ssrc, float* __restrict__ out, int n, int E) {
    __shared__ float red[8][128];
    int node = blockIdx.x;
    int tid = threadIdx.x;
    int c4 = (tid & 31) * 4;
    int slot = tid >> 5;           // 0..7
    float di = dinv[node];
    int s0 = start[node];
    int len = indeg[node];
    if (s0 < 0) s0 = 0;
    if (len < 0) len = 0;
    if (s0 + len > E) len = (E - s0 > 0) ? (E - s0) : 0;

    float4 acc = {0.f, 0.f, 0.f, 0.f};
    for (int j = slot; j < len; j += 8) {
        int s = ssrc[s0 + j];
        if ((unsigned)s >= (unsigned)n) continue;   // defensive: poison -> skip
        float w = dinv[s] * di;
        float4 v = *(const float4*)(h + (size_t)s * 128 + c4);
        acc.x = fmaf(v.x, w, acc.x);
        acc.y = fmaf(v.y, w, acc.y);
        acc.z = fmaf(v.z, w, acc.z);
        acc.w = fmaf(v.w, w, acc.w);
    }
    *(float4*)&red[slot][c4] = acc;
    __syncthreads();
    if (tid < 128) {
        int c = tid;
        float r = h[(size_t)node * 128 + c] * di * di;    // self loop
#pragma unroll
        for (int s = 0; s < 8; ++s) r += red[s][c];       // 2-way bank alias: free
        out[(size_t)node * 128 + c] = r;
    }
}

// C<=64 channels: 256 threads = 4 edge-slots x 64 lanes (scalar).

__global__ __launch_bounds__(256) void aggregateC_par(
        const float* __restrict__ h, const float* __restrict__ dinv,
        const int* __restrict__ start, const int* __restrict__ indeg,
        const int* __restrict__ ssrc, float* __restrict__ out, int n, int C, int E) {
    __shared__ float red[4][64];
    int node = blockIdx.x;
    int tid = threadIdx.x;
    int c = tid & 63;
    int slot = tid >> 6;           // 0..3
    bool act = c < C;
    float di = dinv[node];
    int s0 = start[node];
    int len = indeg[node];
    if (s0 < 0) s0 = 0;
    if (len < 0) len = 0;
    if (s0 + len > E) len = (E - s0 > 0) ? (E - s0) : 0;

    float acc = 0.f;
    for (int j = slot; j < len; j += 4) {
        int s = ssrc[s0 + j];
        if ((unsigned)s >= (unsigned)n) continue;
        if (act) acc = fmaf(h[(size_t)s * C + c], dinv[s] * di, acc);
    }
    red[slot][c] = acc;
    __syncthreads();
    if (tid < 64 && act) {
        float r = h[(size_t)node * C + c] * di * di;
#pragma unroll
        for (int s = 0; s < 4; ++s) r += red[s][c];
        out[(size_t)node * C + c] = r;
    }
}

// ---------------- BatchNorm ----------------

__global__ void bn_stats(const float* __restrict__ x, int n,
                         float* __restrict__ sums, float* __restrict__ sumsq) {
    int c = threadIdx.x;   // 128
    float s = 0.f, s2 = 0.f;
    for (int r = blockIdx.x; r < n; r += gridDim.x) {
        float v = x[(size_t)r * 128 + c];
        s += v; s2 += v * v;
    }
    atomicAdd(&sums[c], s);
    atomicAdd(&sumsq[c], s2);
}

__global__ void bn_finalize(const float* __restrict__ sums, const float* __restrict__ sumsq,
                            const float* __restrict__ g, const float* __restrict__ b,
                            int n, float* __restrict__ A, float* __restrict__ Bout) {
    int c = threadIdx.x;   // 128
    float m = sums[c] / (float)n;
    float v = sumsq[c] / (float)n - m * m;
    float a = g[c] * (1.0f / sqrtf(v + 1e-5f));
    A[c] = a;
    Bout[c] = b[c] - m * a;
}

// BN affine + ReLU + unsigned 4-bit fake-quant (per-node scale gs[row])
__global__ void bn_apply_quant(const float* __restrict__ x, const float* __restrict__ A,
                               const float* __restrict__ Bp, const float* __restrict__ gs,
                               float* __restrict__ out, int n) {
    int idx = blockIdx.x * blockDim.x + threadIdx.x;
    if (idx >= n * 128) return;
    int c = idx & 127;
    int r = idx >> 7;
    float v = A[c] * x[idx] + Bp[c];
    v = fmaxf(v, 0.0f);
    float s = gs[r];
    float q = fminf(fmaxf(v / s, 0.0f), 15.0f);
    out[idx] = rintf(q) * s;
}

// ---------------- log_softmax (one wave per row, in-place safe) ----------------

__global__ void log_softmax_rows(const float* __restrict__ z, float* __restrict__ out,
                                 int n, int C) {
    int rowsPerBlock = blockDim.x / 64;
    int row = blockIdx.x * rowsPerBlock + (threadIdx.x / 64);
    int lane = threadIdx.x & 63;
    if (row >= n) return;
    float v = (lane < C) ? z[(size_t)row * C + lane] : -INFINITY;
    float m = v;
#pragma unroll
    for (int o = 32; o; o >>= 1) m = fmaxf(m, __shfl_xor(m, o));
    float e = (lane < C) ? expf(v - m) : 0.0f;
    float s = e;
#pragma unroll
    for (int o = 32; o; o >>= 1) s += __shfl_xor(s, o);
    if (lane < C) out[(size_t)row * C + lane] = v - m - logf(s);
}

// ---------------- launch ----------------

extern "C" void kernel_launch(void* const* d_in, const int* in_sizes, int n_in,
                              void* d_out, int out_size, void* d_ws, size_t ws_size,
                              hipStream_t stream) {
    float*       xbuf = (float*)d_in[0];          // reused as scratch after layer-1 GEMM
    const int*   ei   = (const int*)d_in[1];
    const float* W1   = (const float*)d_in[2];
    const float* b1   = (const float*)d_in[3];
    const float* a1   = (const float*)d_in[4];
    const float* W2   = (const float*)d_in[5];
    const float* b2   = (const float*)d_in[6];
    const float* a2   = (const float*)d_in[7];
    const float* g2   = (const float*)d_in[8];
    const float* W3   = (const float*)d_in[9];
    const float* b3   = (const float*)d_in[10];
    const float* a3   = (const float*)d_in[11];
    const float* g3   = (const float*)d_in[12];
    const float* bn1g = (const float*)d_in[13];
    const float* bn1b = (const float*)d_in[14];
    const float* bn2g = (const float*)d_in[15];
    const float* bn2b = (const float*)d_in[16];

    const int n = in_sizes[0] / 128;      // 50000
    const int E = in_sizes[1] / 2;        // 800000
    const int C = in_sizes[9] / 128;      // 40
    const int* src = ei;
    const int* dst = ei + E;

    // ---- workspace layout (~30 MB) ----
    char* wsp = (char*)d_ws;
    size_t off = 0;
    auto take = [&](size_t bytes) -> void* {
        void* p = wsp + off;
        off += (bytes + 255) & ~(size_t)255;
        return p;
    };
    int*   indeg   = (int*)take((size_t)n * 4);
    int*   startA  = (int*)take((size_t)n * 4);
    int*   cursor  = (int*)take((size_t)n * 4);
    float* dinv    = (float*)take((size_t)n * 4);
    int*   counter = (int*)take(4);
    int*   ssrc    = (int*)take((size_t)E * 4);
    float* w1q     = (float*)take(128 * 128 * 4);
    float* w2q     = (float*)take(128 * 128 * 4);
    float* w3q     = (float*)take((size_t)128 * C * 4);
    float* stats   = (float*)take(512 * 4);
    float* hbuf    = (float*)take((size_t)n * 128 * 4);

    float* sums  = stats;
    float* sumsq = stats + 128;
    float* bnA   = stats + 256;
    float* bnB   = stats + 384;
    float* outF  = (float*)d_out;

    // ---- graph structure (rebuilt every call; ws is poisoned) ----
    hipMemsetAsync(indeg, 0, (size_t)n * 4, stream);
    hipMemsetAsync(counter, 0, 4, stream);
    count_indeg<<<(E + 255) / 256, 256, 0, stream>>>(dst, E, indeg);
    compute_dinv<<<(n + 255) / 256, 256, 0, stream>>>(indeg, dinv, n);
    make_ranges<<<(n + 255) / 256, 256, 0, stream>>>(indeg, startA, cursor, counter, n);
    fill_csr<<<(E + 255) / 256, 256, 0, stream>>>(src, dst, E, cursor, ssrc);

    // ---- weight fake-quant ----
    quant_w<<<(128 * 128 + 255) / 256, 256, 0, stream>>>(W1, a1, w1q, 128 * 128);
    quant_w<<<(128 * 128 + 255) / 256, 256, 0, stream>>>(W2, a2, w2q, 128 * 128);
    quant_w<<<(128 * C + 255) / 256, 256, 0, stream>>>(W3, a3, w3q, 128 * C);

    const int nElem128 = n * 128;
    const int gElem128 = (nElem128 + 255) / 256;
    dim3 grid128((n + TM - 1) / TM, (128 + TN - 1) / TN);
    dim3 gridC((n + TM - 1) / TM, (C + TN - 1) / TN);

    // ---- layer 1 ----
    gemm_bias_tiled<<<grid128, 256, 0, stream>>>(xbuf, w1q, b1, hbuf, n, 128, 128);
    aggregate128_par<<<n, 256, 0, stream>>>(hbuf, dinv, startA, indeg, ssrc, xbuf, n, E);
    hipMemsetAsync(stats, 0, 256 * 4, stream);
    bn_stats<<<512, 128, 0, stream>>>(xbuf, n, sums, sumsq);
    bn_finalize<<<1, 128, 0, stream>>>(sums, sumsq, bn1g, bn1b, n, bnA, bnB);
    bn_apply_quant<<<gElem128, 256, 0, stream>>>(xbuf, bnA, bnB, g2, hbuf, n);

    // ---- layer 2 ----
    gemm_bias_tiled<<<grid128, 256, 0, stream>>>(hbuf, w2q, b2, xbuf, n, 128, 128);
    aggregate128_par<<<n, 256, 0, stream>>>(xbuf, dinv, startA, indeg, ssrc, hbuf, n, E);
    hipMemsetAsync(stats, 0, 256 * 4, stream);
    bn_stats<<<512, 128, 0, stream>>>(hbuf, n, sums, sumsq);
    bn_finalize<<<1, 128, 0, stream>>>(sums, sumsq, bn2g, bn2b, n, bnA, bnB);
    bn_apply_quant<<<gElem128, 256, 0, stream>>>(hbuf, bnA, bnB, g3, xbuf, n);

    // ---- layer 3 ----
    gemm_bias_tiled<<<gridC, 256, 0, stream>>>(xbuf, w3q, b3, hbuf, n, C, 128);
    aggregateC_par<<<n, 256, 0, stream>>>(hbuf, dinv, startA, indeg, ssrc, outF, n, C, E);
    log_softmax_rows<<<(n + 3) / 4, 256, 0, stream>>>(outF, outF, n, C);
}

// Round 5
// 582.402 us; speedup vs baseline: 2.0290x; 1.0722x over previous
//
#include <hip/hip_runtime.h>
#include <hip/hip_bf16.h>
#include <math.h>

// ---------------- graph structure ----------------

__global__ void count_indeg(const int* __restrict__ dst, int e, int* __restrict__ indeg) {
    int i = blockIdx.x * blockDim.x + threadIdx.x;
    if (i < e) atomicAdd(&indeg[dst[i]], 1);
}

__global__ void compute_dinv(const int* __restrict__ indeg, float* __restrict__ dinv, int n) {
    int i = blockIdx.x * blockDim.x + threadIdx.x;
    if (i < n) {
        float deg = (float)(indeg[i] + 1);   // + self loop, always >= 1
        dinv[i] = 1.0f / sqrtf(deg);
    }
}

// disjoint ranges via one global counter; order across nodes irrelevant
__global__ void make_ranges(const int* __restrict__ indeg, int* __restrict__ start,
                            int* __restrict__ cursor, int* __restrict__ counter, int n) {
    int i = blockIdx.x * blockDim.x + threadIdx.x;
    if (i < n) {
        int s = atomicAdd(counter, indeg[i]);
        start[i] = s;
        cursor[i] = s;
    }
}

__global__ void fill_csr(const int* __restrict__ src, const int* __restrict__ dst, int e,
                         int* __restrict__ cursor, int* __restrict__ ssrc) {
    int i = blockIdx.x * blockDim.x + threadIdx.x;
    if (i < e) {
        int p = atomicAdd(&cursor[dst[i]], 1);
        if (p >= 0 && p < e) ssrc[p] = src[i];
    }
}

// ---------------- weight fake-quant (symmetric 4-bit) ----------------

__global__ void quant_w(const float* __restrict__ w, const float* __restrict__ a,
                        float* __restrict__ wq, int n) {
    int i = blockIdx.x * blockDim.x + threadIdx.x;
    if (i < n) {
        float s = a[0];
        float v = w[i] / s;
        v = fminf(fmaxf(v, -8.0f), 7.0f);
        wq[i] = rintf(v) * s;   // round-half-even, matches jnp.round
    }
}

// ---------------- tiled GEMM: C[M,N] = A[M,K] @ B[K,N] + bias[N] ----------------

#define TM 128
#define TN 64
#define TK 16

__global__ __launch_bounds__(256) void gemm_bias_tiled(
        const float* __restrict__ A, const float* __restrict__ B,
        const float* __restrict__ bias, float* __restrict__ C,
        int M, int N, int K) {
    __shared__ float sA[TK][TM + 4];
    __shared__ float sB[TK][TN + 4];
    int tid = threadIdx.x;
    int rowBase = blockIdx.x * TM;
    int colBase = blockIdx.y * TN;
    int tx = tid & 15;
    int ty = tid >> 4;
    float acc[8][4] = {};

    int aRow = tid >> 1;
    int aK   = (tid & 1) * 8;
    int bK   = tid >> 4;
    int bCol = (tid & 15) * 4;

    for (int k0 = 0; k0 < K; k0 += TK) {
        int gRow = rowBase + aRow;
        if (gRow >= M) gRow = M - 1;            // clamp; discarded at store
        const float* ap = A + (size_t)gRow * K + k0 + aK;
        float4 a0 = *(const float4*)ap;
        float4 a1 = *(const float4*)(ap + 4);
        sA[aK + 0][aRow] = a0.x;
        sA[aK + 1][aRow] = a0.y;
        sA[aK + 2][aRow] = a0.z;
        sA[aK + 3][aRow] = a0.w;
        sA[aK + 4][aRow] = a1.x;
        sA[aK + 5][aRow] = a1.y;
        sA[aK + 6][aRow] = a1.z;
        sA[aK + 7][aRow] = a1.w;

        int col = colBase + bCol;
        const float* bp = B + (size_t)(k0 + bK) * N + col;
        if (col + 3 < N) {
            *(float4*)&sB[bK][bCol] = *(const float4*)bp;
        } else {
#pragma unroll
            for (int j = 0; j < 4; ++j)
                sB[bK][bCol + j] = (col + j < N) ? bp[j] : 0.0f;
        }
        __syncthreads();

#pragma unroll
        for (int kk = 0; kk < TK; ++kk) {
            float4 av0 = *(const float4*)&sA[kk][ty * 8];
            float4 av1 = *(const float4*)&sA[kk][ty * 8 + 4];
            float4 bv  = *(const float4*)&sB[kk][tx * 4];
            float a[8] = {av0.x, av0.y, av0.z, av0.w, av1.x, av1.y, av1.z, av1.w};
            float b[4] = {bv.x, bv.y, bv.z, bv.w};
#pragma unroll
            for (int i = 0; i < 8; ++i)
#pragma unroll
                for (int j = 0; j < 4; ++j)
                    acc[i][j] = fmaf(a[i], b[j], acc[i][j]);
        }
        __syncthreads();
    }

    int colOut = colBase + tx * 4;
    float bb[4];
#pragma unroll
    for (int j = 0; j < 4; ++j) bb[j] = (colOut + j < N) ? bias[colOut + j] : 0.0f;
#pragma unroll
    for (int i = 0; i < 8; ++i) {
        int row = rowBase + ty * 8 + i;
        if (row >= M) continue;
        if (colOut + 3 < N) {
            float4 v = {acc[i][0] + bb[0], acc[i][1] + bb[1],
                        acc[i][2] + bb[2], acc[i][3] + bb[3]};
            *(float4*)&C[(size_t)row * N + colOut] = v;
        } else {
#pragma unroll
            for (int j = 0; j < 4; ++j)
                if (colOut + j < N) C[(size_t)row * N + colOut + j] = acc[i][j] + bb[j];
        }
    }
}

// ---------------- GCN aggregation: LDS-staged indices, edge-parallel ----------------
// 128 ch: 256 threads = 8 slots x 32 lanes x float4. Indices+weights staged in LDS,
// gather loop unrolled x2 -> >=2 independent 512B row gathers in flight per slot.

__global__ __launch_bounds__(256) void aggregate128_par(
        const float* __restrict__ h, const float* __restrict__ dinv,
        const int* __restrict__ start, const int* __restrict__ indeg,
        const int* __restrict__ ssrc, float* __restrict__ out, int n, int E) {
    __shared__ int   sIdx[256];
    __shared__ float sW[256];
    __shared__ float red[8][128];
    int node = blockIdx.x;
    int tid = threadIdx.x;
    int c4 = (tid & 31) * 4;
    int slot = tid >> 5;           // 0..7
    float di = dinv[node];
    int s0 = start[node];
    int len = indeg[node];
    if (s0 < 0) s0 = 0;
    if (len < 0) len = 0;
    if (s0 + len > E) len = (E - s0 > 0) ? (E - s0) : 0;

    float4 acc = {0.f, 0.f, 0.f, 0.f};
    for (int chunk = 0; chunk < len; chunk += 256) {
        int m = len - chunk; if (m > 256) m = 256;
        if (tid < m) {
            int s = ssrc[s0 + chunk + tid];
            if ((unsigned)s >= (unsigned)n) { s = node; sW[tid] = 0.f; }
            else sW[tid] = dinv[s] * di;
            sIdx[tid] = s;
        }
        __syncthreads();
        int j = slot;
        for (; j + 8 < m; j += 16) {
            int sa = sIdx[j], sb = sIdx[j + 8];
            float wa = sW[j], wb = sW[j + 8];
            float4 va = *(const float4*)(h + (size_t)sa * 128 + c4);
            float4 vb = *(const float4*)(h + (size_t)sb * 128 + c4);
            acc.x = fmaf(va.x, wa, acc.x); acc.y = fmaf(va.y, wa, acc.y);
            acc.z = fmaf(va.z, wa, acc.z); acc.w = fmaf(va.w, wa, acc.w);
            acc.x = fmaf(vb.x, wb, acc.x); acc.y = fmaf(vb.y, wb, acc.y);
            acc.z = fmaf(vb.z, wb, acc.z); acc.w = fmaf(vb.w, wb, acc.w);
        }
        if (j < m) {
            int sa = sIdx[j];
            float wa = sW[j];
            float4 va = *(const float4*)(h + (size_t)sa * 128 + c4);
            acc.x = fmaf(va.x, wa, acc.x); acc.y = fmaf(va.y, wa, acc.y);
            acc.z = fmaf(va.z, wa, acc.z); acc.w = fmaf(va.w, wa, acc.w);
        }
        __syncthreads();
    }
    *(float4*)&red[slot][c4] = acc;
    __syncthreads();
    if (tid < 128) {
        int c = tid;
        float r = h[(size_t)node * 128 + c] * di * di;    // self loop
#pragma unroll
        for (int s = 0; s < 8; ++s) r += red[s][c];
        out[(size_t)node * 128 + c] = r;
    }
}

// C<=64 ch (C=40): 8 slots x 32 lanes x float2 (20 active lanes = one 160B row).
// Fused log_softmax epilogue (wave-0 shuffle reduction), writes final output.

__global__ __launch_bounds__(256) void aggregateC_softmax(
        const float* __restrict__ h, const float* __restrict__ dinv,
        const int* __restrict__ start, const int* __restrict__ indeg,
        const int* __restrict__ ssrc, float* __restrict__ out, int n, int C, int E) {
    __shared__ int   sIdx[256];
    __shared__ float sW[256];
    __shared__ float red[8][64];
    int node = blockIdx.x;
    int tid = threadIdx.x;
    int lane = tid & 31;
    int slot = tid >> 5;           // 0..7
    int c2 = lane * 2;
    bool act0 = c2 < C;
    bool act1 = c2 + 1 < C;
    float di = dinv[node];
    int s0 = start[node];
    int len = indeg[node];
    if (s0 < 0) s0 = 0;
    if (len < 0) len = 0;
    if (s0 + len > E) len = (E - s0 > 0) ? (E - s0) : 0;

    float accx = 0.f, accy = 0.f;
    for (int chunk = 0; chunk < len; chunk += 256) {
        int m = len - chunk; if (m > 256) m = 256;
        if (tid < m) {
            int s = ssrc[s0 + chunk + tid];
            if ((unsigned)s >= (unsigned)n) { s = node; sW[tid] = 0.f; }
            else sW[tid] = dinv[s] * di;
            sIdx[tid] = s;
        }
        __syncthreads();
        int j = slot;
        for (; j + 8 < m; j += 16) {
            int sa = sIdx[j], sb = sIdx[j + 8];
            float wa = sW[j], wb = sW[j + 8];
            float2 va = act0 ? *(const float2*)(h + (size_t)sa * C + c2) : make_float2(0.f, 0.f);
            float2 vb = act0 ? *(const float2*)(h + (size_t)sb * C + c2) : make_float2(0.f, 0.f);
            accx = fmaf(va.x, wa, accx); accy = fmaf(va.y, wa, accy);
            accx = fmaf(vb.x, wb, accx); accy = fmaf(vb.y, wb, accy);
        }
        if (j < m) {
            int sa = sIdx[j];
            float wa = sW[j];
            float2 va = act0 ? *(const float2*)(h + (size_t)sa * C + c2) : make_float2(0.f, 0.f);
            accx = fmaf(va.x, wa, accx); accy = fmaf(va.y, wa, accy);
        }
        __syncthreads();
    }
    if (act0) {
        red[slot][c2] = accx;
        if (act1) red[slot][c2 + 1] = accy;
    }
    __syncthreads();
    if (tid < 64) {
        int c = tid;
        bool act = c < C;
        float r = 0.f;
        if (act) {
            r = h[(size_t)node * C + c] * di * di;        // self loop
#pragma unroll
            for (int s = 0; s < 8; ++s) r += red[s][c];   // 2-way bank alias: free
        }
        // fused log_softmax across the 64-lane wave
        float v = act ? r : -INFINITY;
        float mx = v;
#pragma unroll
        for (int o = 32; o; o >>= 1) mx = fmaxf(mx, __shfl_xor(mx, o));
        float e = act ? expf(v - mx) : 0.0f;
        float sm = e;
#pragma unroll
        for (int o = 32; o; o >>= 1) sm += __shfl_xor(sm, o);
        if (act) out[(size_t)node * C + c] = v - mx - logf(sm);
    }
}

// ---------------- BatchNorm ----------------

__global__ void bn_stats(const float* __restrict__ x, int n,
                         float* __restrict__ sums, float* __restrict__ sumsq) {
    int c = threadIdx.x;   // 128
    float s = 0.f, s2 = 0.f;
    for (int r = blockIdx.x; r < n; r += gridDim.x) {
        float v = x[(size_t)r * 128 + c];
        s += v; s2 += v * v;
    }
    atomicAdd(&sums[c], s);
    atomicAdd(&sumsq[c], s2);
}

__global__ void bn_finalize(const float* __restrict__ sums, const float* __restrict__ sumsq,
                            const float* __restrict__ g, const float* __restrict__ b,
                            int n, float* __restrict__ A, float* __restrict__ Bout) {
    int c = threadIdx.x;   // 128
    float m = sums[c] / (float)n;
    float v = sumsq[c] / (float)n - m * m;
    float a = g[c] * (1.0f / sqrtf(v + 1e-5f));
    A[c] = a;
    Bout[c] = b[c] - m * a;
}

// BN affine + ReLU + unsigned 4-bit fake-quant (per-node scale gs[row])
__global__ void bn_apply_quant(const float* __restrict__ x, const float* __restrict__ A,
                               const float* __restrict__ Bp, const float* __restrict__ gs,
                               float* __restrict__ out, int n) {
    int idx = blockIdx.x * blockDim.x + threadIdx.x;
    if (idx >= n * 128) return;
    int c = idx & 127;
    int r = idx >> 7;
    float v = A[c] * x[idx] + Bp[c];
    v = fmaxf(v, 0.0f);
    float s = gs[r];
    float q = fminf(fmaxf(v / s, 0.0f), 15.0f);
    out[idx] = rintf(q) * s;
}

// ---------------- launch ----------------

extern "C" void kernel_launch(void* const* d_in, const int* in_sizes, int n_in,
                              void* d_out, int out_size, void* d_ws, size_t ws_size,
                              hipStream_t stream) {
    float*       xbuf = (float*)d_in[0];          // reused as scratch after layer-1 GEMM
    const int*   ei   = (const int*)d_in[1];
    const float* W1   = (const float*)d_in[2];
    const float* b1   = (const float*)d_in[3];
    const float* a1   = (const float*)d_in[4];
    const float* W2   = (const float*)d_in[5];
    const float* b2   = (const float*)d_in[6];
    const float* a2   = (const float*)d_in[7];
    const float* g2   = (const float*)d_in[8];
    const float* W3   = (const float*)d_in[9];
    const float* b3   = (const float*)d_in[10];
    const float* a3   = (const float*)d_in[11];
    const float* g3   = (const float*)d_in[12];
    const float* bn1g = (const float*)d_in[13];
    const float* bn1b = (const float*)d_in[14];
    const float* bn2g = (const float*)d_in[15];
    const float* bn2b = (const float*)d_in[16];

    const int n = in_sizes[0] / 128;      // 50000
    const int E = in_sizes[1] / 2;        // 800000
    const int C = in_sizes[9] / 128;      // 40
    const int* src = ei;
    const int* dst = ei + E;

    // ---- workspace layout (~30 MB) ----
    char* wsp = (char*)d_ws;
    size_t off = 0;
    auto take = [&](size_t bytes) -> void* {
        void* p = wsp + off;
        off += (bytes + 255) & ~(size_t)255;
        return p;
    };
    int*   indeg   = (int*)take((size_t)n * 4);
    int*   startA  = (int*)take((size_t)n * 4);
    int*   cursor  = (int*)take((size_t)n * 4);
    float* dinv    = (float*)take((size_t)n * 4);
    int*   counter = (int*)take(4);
    int*   ssrc    = (int*)take((size_t)E * 4);
    float* w1q     = (float*)take(128 * 128 * 4);
    float* w2q     = (float*)take(128 * 128 * 4);
    float* w3q     = (float*)take((size_t)128 * C * 4);
    float* stats   = (float*)take(512 * 4);
    float* hbuf    = (float*)take((size_t)n * 128 * 4);

    float* sums  = stats;
    float* sumsq = stats + 128;
    float* bnA   = stats + 256;
    float* bnB   = stats + 384;
    float* outF  = (float*)d_out;

    // ---- graph structure (rebuilt every call; ws is poisoned) ----
    hipMemsetAsync(indeg, 0, (size_t)n * 4, stream);
    hipMemsetAsync(counter, 0, 4, stream);
    count_indeg<<<(E + 255) / 256, 256, 0, stream>>>(dst, E, indeg);
    compute_dinv<<<(n + 255) / 256, 256, 0, stream>>>(indeg, dinv, n);
    make_ranges<<<(n + 255) / 256, 256, 0, stream>>>(indeg, startA, cursor, counter, n);
    fill_csr<<<(E + 255) / 256, 256, 0, stream>>>(src, dst, E, cursor, ssrc);

    // ---- weight fake-quant ----
    quant_w<<<(128 * 128 + 255) / 256, 256, 0, stream>>>(W1, a1, w1q, 128 * 128);
    quant_w<<<(128 * 128 + 255) / 256, 256, 0, stream>>>(W2, a2, w2q, 128 * 128);
    quant_w<<<(128 * C + 255) / 256, 256, 0, stream>>>(W3, a3, w3q, 128 * C);

    const int nElem128 = n * 128;
    const int gElem128 = (nElem128 + 255) / 256;
    dim3 grid128((n + TM - 1) / TM, (128 + TN - 1) / TN);
    dim3 gridC((n + TM - 1) / TM, (C + TN - 1) / TN);

    // ---- layer 1 ----
    gemm_bias_tiled<<<grid128, 256, 0, stream>>>(xbuf, w1q, b1, hbuf, n, 128, 128);
    aggregate128_par<<<n, 256, 0, stream>>>(hbuf, dinv, startA, indeg, ssrc, xbuf, n, E);
    hipMemsetAsync(stats, 0, 256 * 4, stream);
    bn_stats<<<512, 128, 0, stream>>>(xbuf, n, sums, sumsq);
    bn_finalize<<<1, 128, 0, stream>>>(sums, sumsq, bn1g, bn1b, n, bnA, bnB);
    bn_apply_quant<<<gElem128, 256, 0, stream>>>(xbuf, bnA, bnB, g2, hbuf, n);

    // ---- layer 2 ----
    gemm_bias_tiled<<<grid128, 256, 0, stream>>>(hbuf, w2q, b2, xbuf, n, 128, 128);
    aggregate128_par<<<n, 256, 0, stream>>>(xbuf, dinv, startA, indeg, ssrc, hbuf, n, E);
    hipMemsetAsync(stats, 0, 256 * 4, stream);
    bn_stats<<<512, 128, 0, stream>>>(hbuf, n, sums, sumsq);
    bn_finalize<<<1, 128, 0, stream>>>(sums, sumsq, bn2g, bn2b, n, bnA, bnB);
    bn_apply_quant<<<gElem128, 256, 0, stream>>>(hbuf, bnA, bnB, g3, xbuf, n);

    // ---- layer 3 (aggregate + log_softmax fused) ----
    gemm_bias_tiled<<<gridC, 256, 0, stream>>>(xbuf, w3q, b3, hbuf, n, C, 128);
    aggregateC_softmax<<<n, 256, 0, stream>>>(hbuf, dinv, startA, indeg, ssrc, outF, n, C, E);
}